// Round 5
// baseline (1615.973 us; speedup 1.0000x reference)
//
#include <hip/hip_runtime.h>
#include <hip/hip_bf16.h>

#define HID   1024
#define EMB   512
#define BATCH 128
#define TT    256
#define OUTN  4
#define BH    (BATCH * HID)

typedef short bf16x8 __attribute__((ext_vector_type(8)));   // 8 bf16 in 4 VGPRs
typedef float f32x4  __attribute__((ext_vector_type(4)));
typedef int   i32x4  __attribute__((ext_vector_type(4)));

__device__ __forceinline__ float bf2f(unsigned short h) {
    return __uint_as_float(((unsigned)h) << 16);
}
__device__ __forceinline__ unsigned short f2bf(float f) {
    unsigned u = __float_as_uint(f);
    u += 0x7FFFu + ((u >> 16) & 1u);      // RNE
    return (unsigned short)(u >> 16);
}
__device__ __forceinline__ void cvt8(const float* s, unsigned short* d) {
    float4 a = *(const float4*)s, b = *(const float4*)(s + 4);
    unsigned short t[8] = {f2bf(a.x), f2bf(a.y), f2bf(a.z), f2bf(a.w),
                           f2bf(b.x), f2bf(b.y), f2bf(b.z), f2bf(b.w)};
    *(int4*)d = *(const int4*)t;
}
__device__ __forceinline__ bf16x8 pack8(const float* s) {
    float4 a = *(const float4*)s, b = *(const float4*)(s + 4);
    bf16x8 f;
    f[0] = (short)f2bf(a.x); f[1] = (short)f2bf(a.y);
    f[2] = (short)f2bf(a.z); f[3] = (short)f2bf(a.w);
    f[4] = (short)f2bf(b.x); f[5] = (short)f2bf(b.y);
    f[6] = (short)f2bf(b.z); f[7] = (short)f2bf(b.w);
    return f;
}

// ---------------------------------------------------------------------------
// wcvt: one-time wx0 f32 -> bf16 (1 MB) — proven in round 3.
// ---------------------------------------------------------------------------
__global__ __launch_bounds__(256) void wcvt_kernel(
    const float* __restrict__ w, unsigned short* __restrict__ o)
{
    const int i = (blockIdx.x * 256 + threadIdx.x) * 8;   // HID*EMB = 524288
    cvt8(w + i, o + i);
}

// ---------------------------------------------------------------------------
// Phase A: pre0[t*128+b][i] = emb[fx[b][t]] . Wx0[i] + bx0[i] + bh0[i]
// (proven in round 3; bf16 B-fragments)
// ---------------------------------------------------------------------------
__global__ __launch_bounds__(256) void prefx_kernel(
    const int* __restrict__ fx, const float* __restrict__ emb,
    const unsigned short* __restrict__ wx0b, const float* __restrict__ bx0,
    const float* __restrict__ bh0, unsigned short* __restrict__ pre0)
{
    __shared__ __align__(16) unsigned short A[64 * 520];
    const int mtile = blockIdx.x >> 2;
    const int ntile = blockIdx.x & 3;
    const int tid = threadIdx.x;

    {
        const int row = tid >> 2, part = tid & 3;
        const int r = mtile * 64 + row;
        const int t = r >> 7, b = r & 127;
        const int v = fx[b * TT + t];
        const float* src = emb + (size_t)v * EMB + part * 128;
        unsigned short* dst = A + row * 520 + part * 128;
        #pragma unroll
        for (int i = 0; i < 128; i += 8) cvt8(src + i, dst + i);
    }
    __syncthreads();

    const int wave = tid >> 6, lane = tid & 63, q = lane >> 4, nl = lane & 15;
    const int col0 = ntile * 256 + wave * 64;

    f32x4 acc[4][4] = {};
    for (int kc = 0; kc < 16; ++kc) {
        bf16x8 bfr[4], afr[4];
        #pragma unroll
        for (int nt = 0; nt < 4; ++nt)
            bfr[nt] = *(const bf16x8*)(wx0b + (size_t)(col0 + nt * 16 + nl) * EMB + kc * 32 + q * 8);
        #pragma unroll
        for (int mt = 0; mt < 4; ++mt)
            afr[mt] = *(const bf16x8*)(A + (mt * 16 + nl) * 520 + kc * 32 + q * 8);
        #pragma unroll
        for (int mt = 0; mt < 4; ++mt)
            #pragma unroll
            for (int nt = 0; nt < 4; ++nt)
                acc[mt][nt] = __builtin_amdgcn_mfma_f32_16x16x32_bf16(afr[mt], bfr[nt], acc[mt][nt], 0, 0, 0);
    }

    #pragma unroll
    for (int nt = 0; nt < 4; ++nt) {
        const int gc = col0 + nt * 16 + nl;
        const float bias = bx0[gc] + bh0[gc];
        #pragma unroll
        for (int mt = 0; mt < 4; ++mt)
            #pragma unroll
            for (int r = 0; r < 4; ++r) {
                const int grow = mtile * 64 + mt * 16 + q * 4 + r;
                pre0[(size_t)grow * HID + gc] = f2bf(acc[mt][nt][r] + bias);
            }
    }
}

// ---------------------------------------------------------------------------
// MALL-coherent bypass helpers (sc0 sc1) — round-0/3 proven. Every vmem asm
// block ends with s_waitcnt vmcnt(0).
// ---------------------------------------------------------------------------
__device__ __forceinline__ void bypass_store16B(unsigned short* dst, i32x4 v) {
    asm volatile("global_store_dwordx4 %0, %1, off sc0 sc1\n\t"
                 "s_waitcnt vmcnt(0)"
                 :: "v"(dst), "v"(v) : "memory");
}

// 8 x 16B from p2 (strided 64B) + 4 x 16B from p1 (strided 64B)
__device__ __forceinline__ void bypass_load12(const unsigned short* p2,
                                              const unsigned short* p1,
                                              bf16x8 A[8], bf16x8 E[4]) {
    asm volatile(
        "global_load_dwordx4 %0, %12, off sc0 sc1\n\t"
        "global_load_dwordx4 %1, %12, off offset:64 sc0 sc1\n\t"
        "global_load_dwordx4 %2, %12, off offset:128 sc0 sc1\n\t"
        "global_load_dwordx4 %3, %12, off offset:192 sc0 sc1\n\t"
        "global_load_dwordx4 %4, %12, off offset:256 sc0 sc1\n\t"
        "global_load_dwordx4 %5, %12, off offset:320 sc0 sc1\n\t"
        "global_load_dwordx4 %6, %12, off offset:384 sc0 sc1\n\t"
        "global_load_dwordx4 %7, %12, off offset:448 sc0 sc1\n\t"
        "global_load_dwordx4 %8, %13, off sc0 sc1\n\t"
        "global_load_dwordx4 %9, %13, off offset:64 sc0 sc1\n\t"
        "global_load_dwordx4 %10, %13, off offset:128 sc0 sc1\n\t"
        "global_load_dwordx4 %11, %13, off offset:192 sc0 sc1\n\t"
        "s_waitcnt vmcnt(0)"
        : "=&v"(A[0]), "=&v"(A[1]), "=&v"(A[2]), "=&v"(A[3]),
          "=&v"(A[4]), "=&v"(A[5]), "=&v"(A[6]), "=&v"(A[7]),
          "=&v"(E[0]), "=&v"(E[1]), "=&v"(E[2]), "=&v"(E[3])
        : "v"(p2), "v"(p1) : "memory");
}

__device__ __forceinline__ void bypass_ld8_seq(const unsigned short* p, bf16x8 r[8]) {
    asm volatile(
        "global_load_dwordx4 %0, %8, off sc0 sc1\n\t"
        "global_load_dwordx4 %1, %8, off offset:16 sc0 sc1\n\t"
        "global_load_dwordx4 %2, %8, off offset:32 sc0 sc1\n\t"
        "global_load_dwordx4 %3, %8, off offset:48 sc0 sc1\n\t"
        "global_load_dwordx4 %4, %8, off offset:64 sc0 sc1\n\t"
        "global_load_dwordx4 %5, %8, off offset:80 sc0 sc1\n\t"
        "global_load_dwordx4 %6, %8, off offset:96 sc0 sc1\n\t"
        "global_load_dwordx4 %7, %8, off offset:112 sc0 sc1\n\t"
        "s_waitcnt vmcnt(0)"
        : "=&v"(r[0]), "=&v"(r[1]), "=&v"(r[2]), "=&v"(r[3]),
          "=&v"(r[4]), "=&v"(r[5]), "=&v"(r[6]), "=&v"(r[7])
        : "v"(p) : "memory");
}

// ---------------------------------------------------------------------------
// Flag-array cluster barrier — NO atomics, no same-address RMW serialization.
// Each WG plain-stores its step count (sc0 sc1, the mechanism proven for h
// data) to its own slot; thread0 polls all 32 slots with one pipelined batch
// of 8 dwordx4 loads. h-stores are vmcnt(0)-drained (inside their asm) before
// the flag store issues, so flag>=N implies producer data is MALL-visible.
// Counts are monotonically increasing -> no ABA.
// ---------------------------------------------------------------------------
__device__ __forceinline__ void cluster_barrier(unsigned* slotbase, int rank,
                                                unsigned barcount) {
    __syncthreads();
    if (threadIdx.x == 0) {
        asm volatile("global_store_dword %0, %1, off sc0 sc1"
                     :: "v"(slotbase + rank), "v"(barcount) : "memory");
        for (;;) {
            i32x4 r0, r1, r2, r3, r4, r5, r6, r7;
            asm volatile(
                "global_load_dwordx4 %0, %8, off sc0 sc1\n\t"
                "global_load_dwordx4 %1, %8, off offset:16 sc0 sc1\n\t"
                "global_load_dwordx4 %2, %8, off offset:32 sc0 sc1\n\t"
                "global_load_dwordx4 %3, %8, off offset:48 sc0 sc1\n\t"
                "global_load_dwordx4 %4, %8, off offset:64 sc0 sc1\n\t"
                "global_load_dwordx4 %5, %8, off offset:80 sc0 sc1\n\t"
                "global_load_dwordx4 %6, %8, off offset:96 sc0 sc1\n\t"
                "global_load_dwordx4 %7, %8, off offset:112 sc0 sc1\n\t"
                "s_waitcnt vmcnt(0)"
                : "=&v"(r0), "=&v"(r1), "=&v"(r2), "=&v"(r3),
                  "=&v"(r4), "=&v"(r5), "=&v"(r6), "=&v"(r7)
                : "v"(slotbase) : "memory");
            unsigned mn = (unsigned)r0[0];
            #pragma unroll
            for (int k = 1; k < 4; ++k) mn = min(mn, (unsigned)r0[k]);
            #pragma unroll
            for (int k = 0; k < 4; ++k) mn = min(mn, (unsigned)r1[k]);
            #pragma unroll
            for (int k = 0; k < 4; ++k) mn = min(mn, (unsigned)r2[k]);
            #pragma unroll
            for (int k = 0; k < 4; ++k) mn = min(mn, (unsigned)r3[k]);
            #pragma unroll
            for (int k = 0; k < 4; ++k) mn = min(mn, (unsigned)r4[k]);
            #pragma unroll
            for (int k = 0; k < 4; ++k) mn = min(mn, (unsigned)r5[k]);
            #pragma unroll
            for (int k = 0; k < 4; ++k) mn = min(mn, (unsigned)r6[k]);
            #pragma unroll
            for (int k = 0; k < 4; ++k) mn = min(mn, (unsigned)r7[k]);
            if (mn >= barcount) break;
            __builtin_amdgcn_s_sleep(1);
        }
    }
    __syncthreads();
}

// ---------------------------------------------------------------------------
// Phase B: persistent recurrence. 256 WGs x 512 thr, 1 WG/CU (90 KB LDS).
// 8 clusters x 32 WGs; cluster c owns batch rows [16c,16c+16); WG owns 32 cols.
// Superstep t: load [G2(t) + G1(t+1)] -> MFMA -> LDS reduce -> store
// h1(t), h0(t+1) -> one flag barrier. Weights in registers (24 bf16x8 frags).
// Round-3 structure; only change: flag-array barrier (no atomics steady-state).
// ---------------------------------------------------------------------------
__global__ __launch_bounds__(512) void rnn_step_kernel(
    const unsigned short* __restrict__ pre0,
    const float* __restrict__ whh0,
    const float* __restrict__ wx1,
    const float* __restrict__ whh1,
    const float* __restrict__ bx1,
    const float* __restrict__ bh1,
    const float* __restrict__ fcw,
    const float* __restrict__ fcb,
    unsigned short* __restrict__ h0buf,     // [2][128][1024] bf16 (zeroed)
    unsigned short* __restrict__ h1buf,     // [2][128][1024] bf16 (zeroed)
    unsigned* __restrict__ bars,            // 4 KB flag region (zeroed)
    float* __restrict__ out)                // [128][4] f32
{
    __shared__ __align__(16) float ldsbuf[22528];   // 90112 B -> 1 WG/CU
    float* partials = ldsbuf;                                   // [8][4][272]
    unsigned short* hst0 = (unsigned short*)(ldsbuf + 8704);    // [16][32]
    unsigned short* hst1 = (unsigned short*)(ldsbuf + 8704) + 512;
    #define PT(w, t, i) partials[((w) * 4 + (t)) * 272 + (i)]

    const int bid = blockIdx.x;
    const int cluster = bid & 7;
    const int wg = bid >> 3;                 // 0..31
    const int r0 = wg * 32;
    const int tid = threadIdx.x;
    const int wave = tid >> 6, lane = tid & 63, q = lane >> 4, nl = lane & 15;

    // ---- step-invariant weight fragments in registers (24 frags, 96 VGPR) ----
    bf16x8 bw1[2][4], bw2[2][8];
    {
        const int koff1 = wave * 128;                 // G1 chunks wave*4+j
        #pragma unroll
        for (int ct = 0; ct < 2; ++ct)
            #pragma unroll
            for (int j = 0; j < 4; ++j)
                bw1[ct][j] = pack8(whh0 + (size_t)(r0 + ct * 16 + nl) * HID + koff1 + j * 32 + q * 8);
        const float* src2 = (wave < 4) ? wx1 : whh1;  // G2 chunks wave*8+j
        const int koff2 = (wave & 3) * 256;
        #pragma unroll
        for (int ct = 0; ct < 2; ++ct)
            #pragma unroll
            for (int j = 0; j < 8; ++j)
                bw2[ct][j] = pack8(src2 + (size_t)(r0 + ct * 16 + nl) * HID + koff2 + j * 32 + q * 8);
    }

    const int row_r = tid >> 5;              // 0..15: batch row (reduce phase)
    const int col_l = tid & 31;              // 0..31: local HID col
    const int ct_r = (tid >> 4) & 1;         // which 16-col tile
    const float bias1 = bx1[r0 + col_l] + bh1[r0 + col_l];

    const size_t arow = (size_t)(cluster * 16 + nl) * HID + q * 8;
    unsigned barcount = 0;
    unsigned* slotbase = bars + cluster * 64;   // 256B-separated 32-slot blocks

    // ---- prologue: h0(0) = tanh(pre0(0)) (h0 init = 0), store parity 1 ----
    {
        const float pv = bf2f(pre0[(size_t)(cluster * 16 + row_r) * HID + r0 + col_l]);
        hst0[row_r * 32 + col_l] = f2bf(tanhf(pv));
        __syncthreads();
        if (wave == 1) {
            const int row = lane >> 2, seg = (lane & 3) * 8;
            i32x4 v = *(const i32x4*)&hst0[row * 32 + seg];
            bypass_store16B(h0buf + (size_t)BH + (size_t)(cluster * 16 + row) * HID + r0 + seg, v);
        }
        cluster_barrier(slotbase, wg, ++barcount);
    }

    // pre0 pipeline register: value consumed at superstep t is pre0[t+1].
    float pv_cur = bf2f(pre0[(size_t)(BATCH + cluster * 16 + row_r) * HID + r0 + col_l]);

    // ---- main loop: superstep t = [G2(t) || G1(t+1)] ----
    #pragma unroll 1
    for (int t = 0; t < TT - 1; ++t) {
        const int pin = t & 1;
        const unsigned short* h0_cur = h0buf + (size_t)(pin ^ 1) * BH;  // G1(t) out
        unsigned short*       h0_nxt = h0buf + (size_t)pin * BH;        // G1(t+1) dest
        const unsigned short* h1_prv = h1buf + (size_t)pin * BH;        // G2(t-1) out
        unsigned short*       h1_new = h1buf + (size_t)(pin ^ 1) * BH;  // G2(t) dest

        const unsigned short* p2 = (wave < 4 ? h0_cur : h1_prv) + arow + (wave & 3) * 256;
        const unsigned short* p1 = h0_cur + arow + wave * 128;

        bf16x8 A[8], E[4];
        bypass_load12(p2, p1, A, E);

        // prefetch pre0 for the NEXT superstep (HBM-cold line) — issued here,
        // consumed at t+1; its latency hides under MFMA + barrier of step t.
        const int tn = (t + 2 < TT) ? (t + 2) : (TT - 1);
        const float pv_nxt = bf2f(pre0[(size_t)(tn * BATCH + cluster * 16 + row_r) * HID + r0 + col_l]);

        f32x4 d0 = {0.f,0.f,0.f,0.f}, d1 = {0.f,0.f,0.f,0.f};   // G2, tiles 0/1
        f32x4 c0 = {0.f,0.f,0.f,0.f}, c1 = {0.f,0.f,0.f,0.f};   // G1-next
        #pragma unroll
        for (int j = 0; j < 8; ++j) {
            d0 = __builtin_amdgcn_mfma_f32_16x16x32_bf16(A[j], bw2[0][j], d0, 0,0,0);
            d1 = __builtin_amdgcn_mfma_f32_16x16x32_bf16(A[j], bw2[1][j], d1, 0,0,0);
        }
        #pragma unroll
        for (int j = 0; j < 4; ++j) {
            c0 = __builtin_amdgcn_mfma_f32_16x16x32_bf16(E[j], bw1[0][j], c0, 0,0,0);
            c1 = __builtin_amdgcn_mfma_f32_16x16x32_bf16(E[j], bw1[1][j], c1, 0,0,0);
        }

        #pragma unroll
        for (int r = 0; r < 4; ++r) {
            const int idx = (q * 4 + r) * 17 + nl;
            PT(wave, 0, idx) = d0[r];
            PT(wave, 1, idx) = d1[r];
            PT(wave, 2, idx) = c0[r];
            PT(wave, 3, idx) = c1[r];
        }
        __syncthreads();
        {
            const int idx = row_r * 17 + (col_l & 15);
            float s1 = bias1, s0 = pv_cur;
            #pragma unroll
            for (int w = 0; w < 8; ++w) {
                s1 += PT(w, ct_r, idx);
                s0 += PT(w, 2 + ct_r, idx);
            }
            hst1[row_r * 32 + col_l] = f2bf(tanhf(s1));   // h1(t)
            hst0[row_r * 32 + col_l] = f2bf(tanhf(s0));   // h0(t+1)
        }
        __syncthreads();

        if (wave == 0) {
            const int row = lane >> 2, seg = (lane & 3) * 8;
            i32x4 v = *(const i32x4*)&hst1[row * 32 + seg];
            bypass_store16B(h1_new + (size_t)(cluster * 16 + row) * HID + r0 + seg, v);
        } else if (wave == 1) {
            const int row = lane >> 2, seg = (lane & 3) * 8;
            i32x4 v = *(const i32x4*)&hst0[row * 32 + seg];
            bypass_store16B(h0_nxt + (size_t)(cluster * 16 + row) * HID + r0 + seg, v);
        }
        pv_cur = pv_nxt;
        cluster_barrier(slotbase, wg, ++barcount);
    }

    // ---- epilogue: G2(255) -> h1 final (parity 0) ----
    {
        const unsigned short* h0_cur = h0buf;                 // parity 0
        const unsigned short* h1_prv = h1buf + (size_t)BH;    // parity 1
        unsigned short*       h1_new = h1buf;                 // parity 0

        const unsigned short* p2 = (wave < 4 ? h0_cur : h1_prv) + arow + (wave & 3) * 256;
        const unsigned short* p1 = h0_cur + arow + wave * 128;   // dummy (valid mem)

        bf16x8 A[8], E[4];
        bypass_load12(p2, p1, A, E);

        f32x4 d0 = {0.f,0.f,0.f,0.f}, d1 = {0.f,0.f,0.f,0.f};
        #pragma unroll
        for (int j = 0; j < 8; ++j) {
            d0 = __builtin_amdgcn_mfma_f32_16x16x32_bf16(A[j], bw2[0][j], d0, 0,0,0);
            d1 = __builtin_amdgcn_mfma_f32_16x16x32_bf16(A[j], bw2[1][j], d1, 0,0,0);
        }
        #pragma unroll
        for (int r = 0; r < 4; ++r) {
            const int idx = (q * 4 + r) * 17 + nl;
            PT(wave, 0, idx) = d0[r];
            PT(wave, 1, idx) = d1[r];
        }
        __syncthreads();
        {
            const int idx = row_r * 17 + (col_l & 15);
            float s1 = bias1;
            #pragma unroll
            for (int w = 0; w < 8; ++w) s1 += PT(w, ct_r, idx);
            hst1[row_r * 32 + col_l] = f2bf(tanhf(s1));
        }
        __syncthreads();
        if (wave == 0) {
            const int row = lane >> 2, seg = (lane & 3) * 8;
            i32x4 v = *(const i32x4*)&hst1[row * 32 + seg];
            bypass_store16B(h1_new + (size_t)(cluster * 16 + row) * HID + r0 + seg, v);
        }
        cluster_barrier(slotbase, wg, ++barcount);
    }

    // ---- FC head: out = h1_final @ fcw^T + fcb; wg0 of each cluster ----
    if (wg == 0) {
        const int o = tid & 3, row = (tid >> 2) & 15, seg = tid >> 6;  // 8-way K split
        const unsigned short* hp = h1buf + (size_t)(cluster * 16 + row) * HID + seg * 128;
        const float* wp = fcw + (size_t)o * HID + seg * 128;
        float s = 0.f;
        bf16x8 h8[8];
        #pragma unroll 1
        for (int half = 0; half < 2; ++half) {
            bypass_ld8_seq(hp + half * 64, h8);
            #pragma unroll
            for (int i = 0; i < 8; ++i) {
                const float* w = wp + half * 64 + i * 8;
                #pragma unroll
                for (int e = 0; e < 8; ++e)
                    s += bf2f((unsigned short)h8[i][e]) * w[e];
            }
        }
        float* red = ldsbuf;
        red[tid] = s;
        __syncthreads();
        if (tid < 64) {
            float acc = fcb[o];
            #pragma unroll
            for (int sg = 0; sg < 8; ++sg) acc += red[tid + sg * 64];
            out[(cluster * 16 + row) * OUTN + o] = acc;
        }
    }
    #undef PT
}

// ---------------------------------------------------------------------------
extern "C" void kernel_launch(void* const* d_in, const int* in_sizes, int n_in,
                              void* d_out, int out_size, void* d_ws, size_t ws_size,
                              hipStream_t stream) {
    const int*   fx   = (const int*)d_in[0];
    const float* emb  = (const float*)d_in[1];
    const float* wx0  = (const float*)d_in[2];
    const float* bx0  = (const float*)d_in[3];
    const float* whh0 = (const float*)d_in[4];
    const float* bh0  = (const float*)d_in[5];
    const float* wx1  = (const float*)d_in[6];
    const float* bx1  = (const float*)d_in[7];
    const float* whh1 = (const float*)d_in[8];
    const float* bh1  = (const float*)d_in[9];
    const float* fcw  = (const float*)d_in[10];
    const float* fcb  = (const float*)d_in[11];
    float* outp = (float*)d_out;

    // Workspace layout — EXACTLY the proven 68,161,536-byte footprint.
    char* ws = (char*)d_ws;
    unsigned*       bars  = (unsigned*)ws;                              // 4 KB flag slots
    unsigned short* h0buf = (unsigned short*)(ws + 4096);               // 512 KB
    unsigned short* h1buf = (unsigned short*)(ws + 4096 + 524288);      // 512 KB
    unsigned short* pre0  = (unsigned short*)(ws + 4096 + 2 * 524288);  // 64 MB bf16
    // wx0 bf16 scratch (1 MB) occupies h0buf+h1buf (contiguous) during phase
    // A; the second memset re-zeroes them before the persistent kernel.
    unsigned short* wx0b  = h0buf;

    hipMemsetAsync(ws, 0, 4096, stream);                                // flag region

    wcvt_kernel<<<dim3(256), dim3(256), 0, stream>>>(wx0, wx0b);
    prefx_kernel<<<dim3(2048), dim3(256), 0, stream>>>(fx, emb, wx0b, bx0, bh0, pre0);

    hipMemsetAsync(ws + 4096, 0, 2 * 524288, stream);                   // h state zero

    void* kargs[] = {(void*)&pre0, (void*)&whh0, (void*)&wx1, (void*)&whh1,
                     (void*)&bx1, (void*)&bh1, (void*)&fcw, (void*)&fcb,
                     (void*)&h0buf, (void*)&h1buf, (void*)&bars, (void*)&outp};
    hipLaunchCooperativeKernel((void*)rnn_step_kernel, dim3(256), dim3(512),
                               kargs, 0, stream);
}

// Round 6
// 1391.247 us; speedup vs baseline: 1.1615x; 1.1615x over previous
//
#include <hip/hip_runtime.h>
#include <hip/hip_bf16.h>

#define HID   1024
#define EMB   512
#define BATCH 128
#define TT    256
#define OUTN  4
#define BH    (BATCH * HID)

typedef short bf16x8 __attribute__((ext_vector_type(8)));   // 8 bf16 in 4 VGPRs
typedef float f32x4  __attribute__((ext_vector_type(4)));
typedef int   i32x4  __attribute__((ext_vector_type(4)));

__device__ __forceinline__ float bf2f(unsigned short h) {
    return __uint_as_float(((unsigned)h) << 16);
}
__device__ __forceinline__ unsigned short f2bf(float f) {
    unsigned u = __float_as_uint(f);
    u += 0x7FFFu + ((u >> 16) & 1u);      // RNE
    return (unsigned short)(u >> 16);
}
__device__ __forceinline__ void cvt8(const float* s, unsigned short* d) {
    float4 a = *(const float4*)s, b = *(const float4*)(s + 4);
    unsigned short t[8] = {f2bf(a.x), f2bf(a.y), f2bf(a.z), f2bf(a.w),
                           f2bf(b.x), f2bf(b.y), f2bf(b.z), f2bf(b.w)};
    *(int4*)d = *(const int4*)t;
}
__device__ __forceinline__ bf16x8 pack8(const float* s) {
    float4 a = *(const float4*)s, b = *(const float4*)(s + 4);
    bf16x8 f;
    f[0] = (short)f2bf(a.x); f[1] = (short)f2bf(a.y);
    f[2] = (short)f2bf(a.z); f[3] = (short)f2bf(a.w);
    f[4] = (short)f2bf(b.x); f[5] = (short)f2bf(b.y);
    f[6] = (short)f2bf(b.z); f[7] = (short)f2bf(b.w);
    return f;
}

// ---------------------------------------------------------------------------
// wcvt: one-time wx0 f32 -> bf16 (1 MB) — proven in round 3.
// ---------------------------------------------------------------------------
__global__ __launch_bounds__(256) void wcvt_kernel(
    const float* __restrict__ w, unsigned short* __restrict__ o)
{
    const int i = (blockIdx.x * 256 + threadIdx.x) * 8;   // HID*EMB = 524288
    cvt8(w + i, o + i);
}

// ---------------------------------------------------------------------------
// Phase A: pre0[t*128+b][i] = emb[fx[b][t]] . Wx0[i] + bx0[i] + bh0[i]
// (proven in round 3; bf16 B-fragments)
// ---------------------------------------------------------------------------
__global__ __launch_bounds__(256) void prefx_kernel(
    const int* __restrict__ fx, const float* __restrict__ emb,
    const unsigned short* __restrict__ wx0b, const float* __restrict__ bx0,
    const float* __restrict__ bh0, unsigned short* __restrict__ pre0)
{
    __shared__ __align__(16) unsigned short A[64 * 520];
    const int mtile = blockIdx.x >> 2;
    const int ntile = blockIdx.x & 3;
    const int tid = threadIdx.x;

    {
        const int row = tid >> 2, part = tid & 3;
        const int r = mtile * 64 + row;
        const int t = r >> 7, b = r & 127;
        const int v = fx[b * TT + t];
        const float* src = emb + (size_t)v * EMB + part * 128;
        unsigned short* dst = A + row * 520 + part * 128;
        #pragma unroll
        for (int i = 0; i < 128; i += 8) cvt8(src + i, dst + i);
    }
    __syncthreads();

    const int wave = tid >> 6, lane = tid & 63, q = lane >> 4, nl = lane & 15;
    const int col0 = ntile * 256 + wave * 64;

    f32x4 acc[4][4] = {};
    for (int kc = 0; kc < 16; ++kc) {
        bf16x8 bfr[4], afr[4];
        #pragma unroll
        for (int nt = 0; nt < 4; ++nt)
            bfr[nt] = *(const bf16x8*)(wx0b + (size_t)(col0 + nt * 16 + nl) * EMB + kc * 32 + q * 8);
        #pragma unroll
        for (int mt = 0; mt < 4; ++mt)
            afr[mt] = *(const bf16x8*)(A + (mt * 16 + nl) * 520 + kc * 32 + q * 8);
        #pragma unroll
        for (int mt = 0; mt < 4; ++mt)
            #pragma unroll
            for (int nt = 0; nt < 4; ++nt)
                acc[mt][nt] = __builtin_amdgcn_mfma_f32_16x16x32_bf16(afr[mt], bfr[nt], acc[mt][nt], 0, 0, 0);
    }

    #pragma unroll
    for (int nt = 0; nt < 4; ++nt) {
        const int gc = col0 + nt * 16 + nl;
        const float bias = bx0[gc] + bh0[gc];
        #pragma unroll
        for (int mt = 0; mt < 4; ++mt)
            #pragma unroll
            for (int r = 0; r < 4; ++r) {
                const int grow = mtile * 64 + mt * 16 + q * 4 + r;
                pre0[(size_t)grow * HID + gc] = f2bf(acc[mt][nt][r] + bias);
            }
    }
}

// ---------------------------------------------------------------------------
// MALL-coherent bypass helpers (sc0 sc1) — round-0/3 proven. Every vmem asm
// block ends with s_waitcnt vmcnt(0).
// ---------------------------------------------------------------------------
__device__ __forceinline__ void bypass_store16B(unsigned short* dst, i32x4 v) {
    asm volatile("global_store_dwordx4 %0, %1, off sc0 sc1\n\t"
                 "s_waitcnt vmcnt(0)"
                 :: "v"(dst), "v"(v) : "memory");
}

// 8 x 16B from p2 (strided 64B): the wave's K-slice of G2's input (h0 or h1).
__device__ __forceinline__ void bypass_load8A(const unsigned short* p2, bf16x8 A[8]) {
    asm volatile(
        "global_load_dwordx4 %0, %8, off sc0 sc1\n\t"
        "global_load_dwordx4 %1, %8, off offset:64 sc0 sc1\n\t"
        "global_load_dwordx4 %2, %8, off offset:128 sc0 sc1\n\t"
        "global_load_dwordx4 %3, %8, off offset:192 sc0 sc1\n\t"
        "global_load_dwordx4 %4, %8, off offset:256 sc0 sc1\n\t"
        "global_load_dwordx4 %5, %8, off offset:320 sc0 sc1\n\t"
        "global_load_dwordx4 %6, %8, off offset:384 sc0 sc1\n\t"
        "global_load_dwordx4 %7, %8, off offset:448 sc0 sc1\n\t"
        "s_waitcnt vmcnt(0)"
        : "=&v"(A[0]), "=&v"(A[1]), "=&v"(A[2]), "=&v"(A[3]),
          "=&v"(A[4]), "=&v"(A[5]), "=&v"(A[6]), "=&v"(A[7])
        : "v"(p2) : "memory");
}

__device__ __forceinline__ void bypass_ld8_seq(const unsigned short* p, bf16x8 r[8]) {
    asm volatile(
        "global_load_dwordx4 %0, %8, off sc0 sc1\n\t"
        "global_load_dwordx4 %1, %8, off offset:16 sc0 sc1\n\t"
        "global_load_dwordx4 %2, %8, off offset:32 sc0 sc1\n\t"
        "global_load_dwordx4 %3, %8, off offset:48 sc0 sc1\n\t"
        "global_load_dwordx4 %4, %8, off offset:64 sc0 sc1\n\t"
        "global_load_dwordx4 %5, %8, off offset:80 sc0 sc1\n\t"
        "global_load_dwordx4 %6, %8, off offset:96 sc0 sc1\n\t"
        "global_load_dwordx4 %7, %8, off offset:112 sc0 sc1\n\t"
        "s_waitcnt vmcnt(0)"
        : "=&v"(r[0]), "=&v"(r[1]), "=&v"(r[2]), "=&v"(r[3]),
          "=&v"(r[4]), "=&v"(r[5]), "=&v"(r[6]), "=&v"(r[7])
        : "v"(p) : "memory");
}

// Cluster barrier: relaxed agent-scope atomics only (round-0/3 proven).
__device__ __forceinline__ void cluster_barrier(unsigned* bar, unsigned target) {
    __syncthreads();
    if (threadIdx.x == 0) {
        __hip_atomic_fetch_add(bar, 1u, __ATOMIC_RELAXED, __HIP_MEMORY_SCOPE_AGENT);
        while (__hip_atomic_load(bar, __ATOMIC_RELAXED, __HIP_MEMORY_SCOPE_AGENT) < target)
            __builtin_amdgcn_s_sleep(2);
    }
    __syncthreads();
}

// ---------------------------------------------------------------------------
// Phase B: persistent recurrence. 256 WGs x 512 thr, 1 WG/CU (LDS-capped).
// 8 clusters x 32 WGs; cluster c owns batch rows [16c,16c+16); WG owns 32 cols.
// Superstep t: load G2 inputs (h0|h1 K-slices) -> stage h0 through LDS ->
// MFMA G2 -> read G1's h0 fragments from LDS (saves the 32KB/WG MALL re-read)
// -> MFMA G1 -> LDS reduce -> store h1(t), h0(t+1) -> one atomic barrier.
// Weights live in registers (24 bf16x8 frags).
// ---------------------------------------------------------------------------
__global__ __launch_bounds__(512) void rnn_step_kernel(
    const unsigned short* __restrict__ pre0,
    const float* __restrict__ whh0,
    const float* __restrict__ wx1,
    const float* __restrict__ whh1,
    const float* __restrict__ bx1,
    const float* __restrict__ bh1,
    const float* __restrict__ fcw,
    const float* __restrict__ fcb,
    unsigned short* __restrict__ h0buf,     // [2][128][1024] bf16 (zeroed)
    unsigned short* __restrict__ h1buf,     // [2][128][1024] bf16 (zeroed)
    unsigned* __restrict__ bars,            // 4 KB barrier region (zeroed)
    float* __restrict__ out)                // [128][4] f32
{
    __shared__ __align__(16) float ldsbuf[22528];   // 90112 B -> 1 WG/CU
    float* partials = ldsbuf;                                   // [8][4][272]
    unsigned short* hst0 = (unsigned short*)(ldsbuf + 8704);    // [16][32]
    unsigned short* hst1 = (unsigned short*)(ldsbuf + 8704) + 512;
    unsigned short* h0l  = (unsigned short*)(ldsbuf + 9216);    // [16][1032] pad8
    #define PT(w, t, i) partials[((w) * 4 + (t)) * 272 + (i)]

    const int bid = blockIdx.x;
    const int cluster = bid & 7;
    const int wg = bid >> 3;                 // 0..31
    const int r0 = wg * 32;
    const int tid = threadIdx.x;
    const int wave = tid >> 6, lane = tid & 63, q = lane >> 4, nl = lane & 15;

    // ---- step-invariant weight fragments in registers (24 frags, 96 VGPR) ----
    bf16x8 bw1[2][4], bw2[2][8];
    {
        const int koff1 = wave * 128;                 // G1 chunks wave*4+j
        #pragma unroll
        for (int ct = 0; ct < 2; ++ct)
            #pragma unroll
            for (int j = 0; j < 4; ++j)
                bw1[ct][j] = pack8(whh0 + (size_t)(r0 + ct * 16 + nl) * HID + koff1 + j * 32 + q * 8);
        const float* src2 = (wave < 4) ? wx1 : whh1;  // G2 chunks wave*8+j
        const int koff2 = (wave & 3) * 256;
        #pragma unroll
        for (int ct = 0; ct < 2; ++ct)
            #pragma unroll
            for (int j = 0; j < 8; ++j)
                bw2[ct][j] = pack8(src2 + (size_t)(r0 + ct * 16 + nl) * HID + koff2 + j * 32 + q * 8);
    }

    const int row_r = tid >> 5;              // 0..15: batch row (reduce phase)
    const int col_l = tid & 31;              // 0..31: local HID col
    const int ct_r = (tid >> 4) & 1;         // which 16-col tile
    const float bias1 = bx1[r0 + col_l] + bh1[r0 + col_l];

    const size_t arow = (size_t)(cluster * 16 + nl) * HID + q * 8;
    unsigned barcount = 0;
    unsigned* bar = bars + cluster * 64;     // 256B-separated counters

    // LDS staging addresses (h0l row stride 1032 shorts = 2064B -> 2-way banks)
    unsigned short* h0l_w = h0l + nl * 1032 + (wave & 3) * 256 + q * 8;  // write (waves 0-3)
    const unsigned short* h0l_r = h0l + nl * 1032 + wave * 128 + q * 8;  // E-read (all)

    // ---- prologue: h0(0) = tanh(pre0(0)) (h0 init = 0), store parity 1 ----
    {
        const float pv = bf2f(pre0[(size_t)(cluster * 16 + row_r) * HID + r0 + col_l]);
        hst0[row_r * 32 + col_l] = f2bf(tanhf(pv));
        __syncthreads();
        if (wave == 1) {
            const int row = lane >> 2, seg = (lane & 3) * 8;
            i32x4 v = *(const i32x4*)&hst0[row * 32 + seg];
            bypass_store16B(h0buf + (size_t)BH + (size_t)(cluster * 16 + row) * HID + r0 + seg, v);
        }
        cluster_barrier(bar, ++barcount * 32u);
    }

    // pre0 pipeline register: value consumed at superstep t is pre0[t+1].
    float pv_cur = bf2f(pre0[(size_t)(BATCH + cluster * 16 + row_r) * HID + r0 + col_l]);

    // ---- main loop: superstep t = [G2(t) || G1(t+1)] ----
    #pragma unroll 1
    for (int t = 0; t < TT - 1; ++t) {
        const int pin = t & 1;
        const unsigned short* h0_cur = h0buf + (size_t)(pin ^ 1) * BH;  // G1(t) out
        unsigned short*       h0_nxt = h0buf + (size_t)pin * BH;        // G1(t+1) dest
        const unsigned short* h1_prv = h1buf + (size_t)pin * BH;        // G2(t-1) out
        unsigned short*       h1_new = h1buf + (size_t)(pin ^ 1) * BH;  // G2(t) dest

        const unsigned short* p2 = (wave < 4 ? h0_cur : h1_prv) + arow + (wave & 3) * 256;

        bf16x8 A[8];
        bypass_load8A(p2, A);

        // stage h0 K-slices to LDS (waves 0-3 hold all of h0 in their A regs)
        if (wave < 4) {
            #pragma unroll
            for (int j = 0; j < 8; ++j)
                *(bf16x8*)(h0l_w + j * 32) = A[j];
        }

        // prefetch pre0 for the NEXT superstep (HBM-cold line) — issued here,
        // consumed at t+1; its latency hides under MFMA + barrier of step t.
        const int tn = (t + 2 < TT) ? (t + 2) : (TT - 1);
        const float pv_nxt = bf2f(pre0[(size_t)(tn * BATCH + cluster * 16 + row_r) * HID + r0 + col_l]);

        f32x4 d0 = {0.f,0.f,0.f,0.f}, d1 = {0.f,0.f,0.f,0.f};   // G2, tiles 0/1
        #pragma unroll
        for (int j = 0; j < 8; ++j) {
            d0 = __builtin_amdgcn_mfma_f32_16x16x32_bf16(A[j], bw2[0][j], d0, 0,0,0);
            d1 = __builtin_amdgcn_mfma_f32_16x16x32_bf16(A[j], bw2[1][j], d1, 0,0,0);
        }

        __syncthreads();    // h0l ready

        f32x4 c0 = {0.f,0.f,0.f,0.f}, c1 = {0.f,0.f,0.f,0.f};   // G1-next
        #pragma unroll
        for (int j = 0; j < 4; ++j) {
            bf16x8 E = *(const bf16x8*)(h0l_r + j * 32);
            c0 = __builtin_amdgcn_mfma_f32_16x16x32_bf16(E, bw1[0][j], c0, 0,0,0);
            c1 = __builtin_amdgcn_mfma_f32_16x16x32_bf16(E, bw1[1][j], c1, 0,0,0);
        }

        #pragma unroll
        for (int r = 0; r < 4; ++r) {
            const int idx = (q * 4 + r) * 17 + nl;
            PT(wave, 0, idx) = d0[r];
            PT(wave, 1, idx) = d1[r];
            PT(wave, 2, idx) = c0[r];
            PT(wave, 3, idx) = c1[r];
        }
        __syncthreads();
        {
            const int idx = row_r * 17 + (col_l & 15);
            float s1 = bias1, s0 = pv_cur;
            #pragma unroll
            for (int w = 0; w < 8; ++w) {
                s1 += PT(w, ct_r, idx);
                s0 += PT(w, 2 + ct_r, idx);
            }
            hst1[row_r * 32 + col_l] = f2bf(tanhf(s1));   // h1(t)
            hst0[row_r * 32 + col_l] = f2bf(tanhf(s0));   // h0(t+1)
        }
        __syncthreads();

        if (wave == 0) {
            const int row = lane >> 2, seg = (lane & 3) * 8;
            i32x4 v = *(const i32x4*)&hst1[row * 32 + seg];
            bypass_store16B(h1_new + (size_t)(cluster * 16 + row) * HID + r0 + seg, v);
        } else if (wave == 1) {
            const int row = lane >> 2, seg = (lane & 3) * 8;
            i32x4 v = *(const i32x4*)&hst0[row * 32 + seg];
            bypass_store16B(h0_nxt + (size_t)(cluster * 16 + row) * HID + r0 + seg, v);
        }
        pv_cur = pv_nxt;
        cluster_barrier(bar, ++barcount * 32u);
    }

    // ---- epilogue: G2(255) -> h1 final (parity 0) ----
    {
        const unsigned short* h0_cur = h0buf;                 // parity 0
        const unsigned short* h1_prv = h1buf + (size_t)BH;    // parity 1
        unsigned short*       h1_new = h1buf;                 // parity 0

        const unsigned short* p2 = (wave < 4 ? h0_cur : h1_prv) + arow + (wave & 3) * 256;

        bf16x8 A[8];
        bypass_load8A(p2, A);

        f32x4 d0 = {0.f,0.f,0.f,0.f}, d1 = {0.f,0.f,0.f,0.f};
        #pragma unroll
        for (int j = 0; j < 8; ++j) {
            d0 = __builtin_amdgcn_mfma_f32_16x16x32_bf16(A[j], bw2[0][j], d0, 0,0,0);
            d1 = __builtin_amdgcn_mfma_f32_16x16x32_bf16(A[j], bw2[1][j], d1, 0,0,0);
        }
        #pragma unroll
        for (int r = 0; r < 4; ++r) {
            const int idx = (q * 4 + r) * 17 + nl;
            PT(wave, 0, idx) = d0[r];
            PT(wave, 1, idx) = d1[r];
        }
        __syncthreads();
        {
            const int idx = row_r * 17 + (col_l & 15);
            float s1 = bias1;
            #pragma unroll
            for (int w = 0; w < 8; ++w) s1 += PT(w, ct_r, idx);
            hst1[row_r * 32 + col_l] = f2bf(tanhf(s1));
        }
        __syncthreads();
        if (wave == 0) {
            const int row = lane >> 2, seg = (lane & 3) * 8;
            i32x4 v = *(const i32x4*)&hst1[row * 32 + seg];
            bypass_store16B(h1_new + (size_t)(cluster * 16 + row) * HID + r0 + seg, v);
        }
        cluster_barrier(bar, ++barcount * 32u);
    }

    // ---- FC head: out = h1_final @ fcw^T + fcb; wg0 of each cluster ----
    if (wg == 0) {
        const int o = tid & 3, row = (tid >> 2) & 15, seg = tid >> 6;  // 8-way K split
        const unsigned short* hp = h1buf + (size_t)(cluster * 16 + row) * HID + seg * 128;
        const float* wp = fcw + (size_t)o * HID + seg * 128;
        float s = 0.f;
        bf16x8 h8[8];
        #pragma unroll 1
        for (int half = 0; half < 2; ++half) {
            bypass_ld8_seq(hp + half * 64, h8);
            #pragma unroll
            for (int i = 0; i < 8; ++i) {
                const float* w = wp + half * 64 + i * 8;
                #pragma unroll
                for (int e = 0; e < 8; ++e)
                    s += bf2f((unsigned short)h8[i][e]) * w[e];
            }
        }
        float* red = ldsbuf;
        red[tid] = s;
        __syncthreads();
        if (tid < 64) {
            float acc = fcb[o];
            #pragma unroll
            for (int sg = 0; sg < 8; ++sg) acc += red[tid + sg * 64];
            out[(cluster * 16 + row) * OUTN + o] = acc;
        }
    }
    #undef PT
}

// ---------------------------------------------------------------------------
extern "C" void kernel_launch(void* const* d_in, const int* in_sizes, int n_in,
                              void* d_out, int out_size, void* d_ws, size_t ws_size,
                              hipStream_t stream) {
    const int*   fx   = (const int*)d_in[0];
    const float* emb  = (const float*)d_in[1];
    const float* wx0  = (const float*)d_in[2];
    const float* bx0  = (const float*)d_in[3];
    const float* whh0 = (const float*)d_in[4];
    const float* bh0  = (const float*)d_in[5];
    const float* wx1  = (const float*)d_in[6];
    const float* bx1  = (const float*)d_in[7];
    const float* whh1 = (const float*)d_in[8];
    const float* bh1  = (const float*)d_in[9];
    const float* fcw  = (const float*)d_in[10];
    const float* fcb  = (const float*)d_in[11];
    float* outp = (float*)d_out;

    // Workspace layout — EXACTLY the proven 68,161,536-byte footprint.
    char* ws = (char*)d_ws;
    unsigned*       bars  = (unsigned*)ws;                              // 4 KB
    unsigned short* h0buf = (unsigned short*)(ws + 4096);               // 512 KB
    unsigned short* h1buf = (unsigned short*)(ws + 4096 + 524288);      // 512 KB
    unsigned short* pre0  = (unsigned short*)(ws + 4096 + 2 * 524288);  // 64 MB bf16
    // wx0 bf16 scratch (1 MB) occupies h0buf+h1buf (contiguous) during phase
    // A; the second memset re-zeroes them before the persistent kernel.
    unsigned short* wx0b  = h0buf;

    hipMemsetAsync(ws, 0, 4096, stream);                                // barriers

    wcvt_kernel<<<dim3(256), dim3(256), 0, stream>>>(wx0, wx0b);
    prefx_kernel<<<dim3(2048), dim3(256), 0, stream>>>(fx, emb, wx0b, bx0, bh0, pre0);

    hipMemsetAsync(ws + 4096, 0, 2 * 524288, stream);                   // h state zero

    void* kargs[] = {(void*)&pre0, (void*)&whh0, (void*)&wx1, (void*)&whh1,
                     (void*)&bx1, (void*)&bh1, (void*)&fcw, (void*)&fcb,
                     (void*)&h0buf, (void*)&h1buf, (void*)&bars, (void*)&outp};
    hipLaunchCooperativeKernel((void*)rnn_step_kernel, dim3(256), dim3(512),
                               kargs, 0, stream);
}